// Round 1
// baseline (238.803 us; speedup 1.0000x reference)
//
#include <hip/hip_runtime.h>
#include <stdint.h>
#include <math.h>

// BSRBF-KAN layer: out = relu(LN(x)) @ base_W^T + (bspline(LN(x)) + rbf(LN(x))) @ spline_W^T
// Strategy: fold into ONE bf16 MFMA GEMM with K = 512 + 512*8 = 4608.
//   ws layout: [W: 512*4608 bf16][A: 16384*4608 bf16]  (~156 MB total)
// GEMM is m97-structure: 128x128 tile, BK=32, 4 waves, 16x16x32 bf16 MFMA,
// global_load_lds width=16 staging.

#define D_IN  512
#define D_OUT 512
#define NB    8
#define KTOT  (D_IN + D_IN * NB)   // 4608
#define ROWS  16384                // B*S

typedef __attribute__((ext_vector_type(8))) short short8;
typedef __attribute__((ext_vector_type(4))) float f32x4;

__device__ __forceinline__ short f2bf(float f) {
  union { float f; unsigned u; } v; v.f = f;
  unsigned r = (v.u + 0x7fffu + ((v.u >> 16) & 1u)) >> 16;  // RNE, finite inputs
  return (short)r;
}

// knot grid identical to reference: grid[i] = (i-3)*0.6f + (-1.5f), i in [0,12)
__device__ __forceinline__ float knot(int i) {
  return (float)(i - 3) * 0.6f - 1.5f;
}

// ---------------- weight prep: interleave + fp32->bf16 -------------------
__global__ __launch_bounds__(256) void wprep_kernel(
    const float* __restrict__ bw, const float* __restrict__ sw,
    short* __restrict__ W) {
  const int o = blockIdx.x;
  for (int k = threadIdx.x; k < KTOT; k += 256) {
    const float v = (k < D_IN) ? bw[o * D_IN + k]
                               : sw[(size_t)o * (D_IN * NB) + (k - D_IN)];
    W[(size_t)o * KTOT + k] = f2bf(v);
  }
}

// ---------------- LN + relu + bspline + rbf -> bf16 A matrix -------------
__global__ __launch_bounds__(256) void act_kernel(
    const float* __restrict__ x, const float* __restrict__ gamma,
    const float* __restrict__ beta, short* __restrict__ A) {
  const int row = blockIdx.x;
  const int tid = threadIdx.x;
  const int lane = tid & 63, wave = tid >> 6;
  const float* xr = x + (size_t)row * D_IN;
  const float2 xv = *(const float2*)&xr[2 * tid];
  float s = xv.x + xv.y;
  float ss = xv.x * xv.x + xv.y * xv.y;
#pragma unroll
  for (int off = 32; off > 0; off >>= 1) {
    s += __shfl_down(s, off);
    ss += __shfl_down(ss, off);
  }
  __shared__ float red[8];
  if (lane == 0) { red[wave] = s; red[4 + wave] = ss; }
  __syncthreads();
  s = red[0] + red[1] + red[2] + red[3];
  ss = red[4] + red[5] + red[6] + red[7];
  const float mu = s * (1.0f / D_IN);
  const float var = ss * (1.0f / D_IN) - mu * mu;
  const float rstd = 1.0f / sqrtf(var + 1e-5f);
  const float2 gv = *(const float2*)&gamma[2 * tid];
  const float2 bv = *(const float2*)&beta[2 * tid];
  short* Ar = A + (size_t)row * KTOT;
  unsigned relupack = 0;
#pragma unroll
  for (int e = 0; e < 2; e++) {
    const int d = 2 * tid + e;
    const float xs = e ? xv.y : xv.x;
    const float ga = e ? gv.y : gv.x;
    const float be = e ? bv.y : bv.x;
    const float xn = (xs - mu) * rstd * ga + be;
    relupack |= ((unsigned)(unsigned short)f2bf(fmaxf(xn, 0.0f))) << (16 * e);
    // order-0 indicators over 11 cells
    float b[11];
#pragma unroll
    for (int i = 0; i < 11; i++)
      b[i] = (xn >= knot(i) && xn < knot(i + 1)) ? 1.0f : 0.0f;
    // de Boor, uniform knots: denominators are k*h
#pragma unroll
    for (int k = 1; k <= 3; k++) {
      const float invk = 1.0f / (0.6f * (float)k);
#pragma unroll
      for (int i = 0; i + k < 11; i++) {
        const float left = (xn - knot(i)) * invk;
        const float right = (knot(i + k + 1) - xn) * invk;
        b[i] = left * b[i] + right * b[i + 1];
      }
    }
    union { short sh[8]; int4 v; } u;
#pragma unroll
    for (int j = 0; j < 8; j++) {
      const float g = -1.5f + (float)j * (3.0f / 7.0f);
      const float t = (xn - g) * (7.0f / 3.0f);
      u.sh[j] = f2bf(b[j] + __expf(-(t * t)));
    }
    *(int4*)&Ar[D_IN + d * NB] = u.v;  // 16B aligned: (512 + 8d)*2
  }
  *(unsigned*)&Ar[2 * tid] = relupack;
}

// ---------------- bf16 MFMA GEMM: C[M,N] = A[M,K] * W[N,K]^T -------------
#define GLL(g, l)                                               \
  __builtin_amdgcn_global_load_lds(                             \
      (const __attribute__((address_space(1))) void*)(g),       \
      (__attribute__((address_space(3))) void*)(l), 16, 0, 0)

__global__ __launch_bounds__(256, 2) void gemm_kernel(
    const short* __restrict__ A, const short* __restrict__ W,
    float* __restrict__ out) {
  __shared__ short As[128 * 32];
  __shared__ short Bs[128 * 32];
  const int tid = threadIdx.x;
  const int lane = tid & 63, wave = tid >> 6;
  const int m0 = blockIdx.x * 128;
  const int n0 = blockIdx.y * 128;
  const int wm = wave & 1, wn = wave >> 1;

  const f32x4 zero = {0.0f, 0.0f, 0.0f, 0.0f};
  f32x4 acc[4][4];
#pragma unroll
  for (int i = 0; i < 4; i++)
#pragma unroll
    for (int j = 0; j < 4; j++) acc[i][j] = zero;

  // staging: element e = (c*256 + tid)*8 -> LDS[e], row = e/32, k = e%32
  const int r0 = tid >> 2;
  const int kk = (tid & 3) * 8;
  const short* gA0 = A + (size_t)(m0 + r0) * KTOT + kk;
  const short* gA1 = A + (size_t)(m0 + 64 + r0) * KTOT + kk;
  const short* gB0 = W + (size_t)(n0 + r0) * KTOT + kk;
  const short* gB1 = W + (size_t)(n0 + 64 + r0) * KTOT + kk;
  short* lA0 = As + wave * 512;          // wave-uniform LDS base (lane*16B HW)
  short* lA1 = As + 2048 + wave * 512;
  short* lB0 = Bs + wave * 512;
  short* lB1 = Bs + 2048 + wave * 512;

  const int lr = lane & 15;
  const int lk = (lane >> 4) * 8;

  for (int kt = 0; kt < KTOT; kt += 32) {
    __syncthreads();
    GLL(gA0 + kt, lA0);
    GLL(gA1 + kt, lA1);
    GLL(gB0 + kt, lB0);
    GLL(gB1 + kt, lB1);
    __syncthreads();
    short8 af[4], bf[4];
#pragma unroll
    for (int mi = 0; mi < 4; mi++)
      af[mi] = *(const short8*)&As[(wm * 64 + mi * 16 + lr) * 32 + lk];
#pragma unroll
    for (int nj = 0; nj < 4; nj++)
      bf[nj] = *(const short8*)&Bs[(wn * 64 + nj * 16 + lr) * 32 + lk];
#pragma unroll
    for (int mi = 0; mi < 4; mi++)
#pragma unroll
      for (int nj = 0; nj < 4; nj++)
        acc[mi][nj] = __builtin_amdgcn_mfma_f32_16x16x32_bf16(
            af[mi], bf[nj], acc[mi][nj], 0, 0, 0);
  }

  // C/D layout (m89-verified): col = lane&15, row = (lane>>4)*4 + reg
  const int q = lane >> 4;
#pragma unroll
  for (int mi = 0; mi < 4; mi++) {
#pragma unroll
    for (int nj = 0; nj < 4; nj++) {
      const int gcol = n0 + wn * 64 + nj * 16 + lr;
#pragma unroll
      for (int r = 0; r < 4; r++) {
        const int grow = m0 + wm * 64 + mi * 16 + q * 4 + r;
        out[(size_t)grow * D_OUT + gcol] = acc[mi][nj][r];
      }
    }
  }
}

extern "C" void kernel_launch(void* const* d_in, const int* in_sizes, int n_in,
                              void* d_out, int out_size, void* d_ws, size_t ws_size,
                              hipStream_t stream) {
  const float* x     = (const float*)d_in[0];
  const float* gamma = (const float*)d_in[1];
  const float* beta  = (const float*)d_in[2];
  const float* bw    = (const float*)d_in[3];
  const float* sw    = (const float*)d_in[4];
  float* out = (float*)d_out;

  short* W = (short*)d_ws;                       // 512 * 4608 bf16
  short* A = (short*)d_ws + (size_t)D_OUT * KTOT;  // 16384 * 4608 bf16

  wprep_kernel<<<D_OUT, 256, 0, stream>>>(bw, sw, W);
  act_kernel<<<ROWS, 256, 0, stream>>>(x, gamma, beta, A);
  gemm_kernel<<<dim3(ROWS / 128, D_OUT / 128), 256, 0, stream>>>(A, W, out);
}

// Round 2
// 233.506 us; speedup vs baseline: 1.0227x; 1.0227x over previous
//
#include <hip/hip_runtime.h>
#include <stdint.h>
#include <math.h>

// BSRBF-KAN layer: out = relu(LN(x)) @ base_W^T + (bspline(LN(x)) + rbf(LN(x))) @ spline_W^T
// One bf16 MFMA GEMM with K = 512 + 512*8 = 4608.
//   ws layout: [W: 512*4608 bf16][A: 16384*4608 bf16]
// GEMM: 128x64 tile (grid 1024 = 4 blocks/CU), BK=32, 4 waves, 16x16x32 bf16
// MFMA, global_load_lds width=16 staging, XOR bank swizzle.
// act: wave-per-row, closed-form cubic B-spline + RBF, no barriers.

#define D_IN  512
#define D_OUT 512
#define NB    8
#define KTOT  (D_IN + D_IN * NB)   // 4608
#define ROWS  16384                // B*S

typedef __attribute__((ext_vector_type(8))) short short8;
typedef __attribute__((ext_vector_type(4))) float f32x4;

__device__ __forceinline__ short f2bf(float f) {
  union { float f; unsigned u; } v; v.f = f;
  unsigned r = (v.u + 0x7fffu + ((v.u >> 16) & 1u)) >> 16;  // RNE, finite inputs
  return (short)r;
}

// ---------------- weight prep: interleave + fp32->bf16 -------------------
__global__ __launch_bounds__(256) void wprep_kernel(
    const float* __restrict__ bw, const float* __restrict__ sw,
    short* __restrict__ W) {
  const int o = blockIdx.x;
  for (int k = threadIdx.x; k < KTOT; k += 256) {
    const float v = (k < D_IN) ? bw[o * D_IN + k]
                               : sw[(size_t)o * (D_IN * NB) + (k - D_IN)];
    W[(size_t)o * KTOT + k] = f2bf(v);
  }
}

// ---------------- LN + relu + bspline + rbf -> bf16 A matrix -------------
// one wave per row; lane owns elements d = e*64 + lane, e in [0,8)
__global__ __launch_bounds__(256) void act_kernel(
    const float* __restrict__ x, const float* __restrict__ gamma,
    const float* __restrict__ beta, short* __restrict__ A) {
  const int tid = threadIdx.x;
  const int lane = tid & 63, wave = tid >> 6;
  const int row = blockIdx.x * 4 + wave;
  const float* xr = x + (size_t)row * D_IN;

  float xv[8];
  float s = 0.0f, ss = 0.0f;
#pragma unroll
  for (int e = 0; e < 8; e++) {
    xv[e] = xr[e * 64 + lane];
    s += xv[e];
    ss += xv[e] * xv[e];
  }
#pragma unroll
  for (int off = 32; off > 0; off >>= 1) {
    s += __shfl_xor(s, off);
    ss += __shfl_xor(ss, off);
  }
  const float mu = s * (1.0f / D_IN);
  const float var = ss * (1.0f / D_IN) - mu * mu;
  const float rstd = 1.0f / sqrtf(var + 1e-5f);

  short* Ar = A + (size_t)row * KTOT;
#pragma unroll
  for (int e = 0; e < 8; e++) {
    const int d = e * 64 + lane;
    const float xn = (xv[e] - mu) * rstd * gamma[d] + beta[d];
    Ar[d] = f2bf(fmaxf(xn, 0.0f));

    // closed-form uniform cubic B-spline: knots knot(i) = (i-3)*0.6 - 1.5,
    // u = (xn - knot(0))/h, cell c = floor(u); nonzero bases j = c-3..c with
    //   m = c - j: v0=t^3/6, v1=(1+3t+3t^2-3t^3)/6, v2=(3t^3-6t^2+4)/6,
    //   v3=(1-t)^3/6  (t = frac(u))
    const float u = (xn + 3.3f) * (1.0f / 0.6f);
    const float cf = floorf(u);
    const int c = (int)cf;
    const bool in = (c >= 0) && (c <= 10);
    const float t = u - cf;
    const float t2 = t * t, t3 = t2 * t;
    const float omt = 1.0f - t;
    float v0 = t3 * (1.0f / 6.0f);
    float v1 = (1.0f / 6.0f) * (1.0f + 3.0f * t + 3.0f * t2 - 3.0f * t3);
    float v2 = (1.0f / 6.0f) * (4.0f - 6.0f * t2 + 3.0f * t3);
    float v3 = (1.0f / 6.0f) * omt * omt * omt;
    if (!in) { v0 = 0.0f; v1 = 0.0f; v2 = 0.0f; v3 = 0.0f; }

    union { short sh[8]; int4 v; } o;
#pragma unroll
    for (int j = 0; j < 8; j++) {
      const int m = c - j;
      float sp = 0.0f;
      sp = (m == 0) ? v0 : sp;
      sp = (m == 1) ? v1 : sp;
      sp = (m == 2) ? v2 : sp;
      sp = (m == 3) ? v3 : sp;
      // rbf: exp(-((xn - g_j)/denom)^2), g_j = -1.5 + j*(3/7), denom = 3/7
      const float tt = (xn - (-1.5f + (float)j * (3.0f / 7.0f))) * (7.0f / 3.0f);
      const float rb = __builtin_amdgcn_exp2f(tt * tt * -1.442695040888963f);
      o.sh[j] = f2bf(sp + rb);
    }
    *(int4*)&Ar[D_IN + d * NB] = o.v;  // 16B aligned, coalesced across lanes
  }
}

// ---------------- bf16 MFMA GEMM: C[M,N] = A[M,K] * W[N,K]^T -------------
#define GLL(g, l)                                               \
  __builtin_amdgcn_global_load_lds(                             \
      (const __attribute__((address_space(1))) void*)(g),       \
      (__attribute__((address_space(3))) void*)(l), 16, 0, 0)

__global__ __launch_bounds__(256, 4) void gemm_kernel(
    const short* __restrict__ A, const short* __restrict__ W,
    float* __restrict__ out) {
  __shared__ short As[128 * 32];  // 8 KB
  __shared__ short Bs[64 * 32];   // 4 KB
  const int tid = threadIdx.x;
  const int lane = tid & 63, wave = tid >> 6;
  const int m0 = blockIdx.x * 128;
  const int n0 = blockIdx.y * 64;
  const int wm = wave & 1, wn = wave >> 1;  // 2x2 wave grid: 64 rows x 32 cols

  const f32x4 zero = {0.0f, 0.0f, 0.0f, 0.0f};
  f32x4 acc[4][2];
#pragma unroll
  for (int i = 0; i < 4; i++)
#pragma unroll
    for (int j = 0; j < 2; j++) acc[i][j] = zero;

  // staging: LDS row r0, chunk-slot c0 holds global chunk qA = c0 ^ ((r0>>1)&3)
  const int r0 = tid >> 2;
  const int c0 = tid & 3;
  const int qA = c0 ^ ((r0 >> 1) & 3);
  const int kk = qA * 8;
  const short* gA0 = A + (size_t)(m0 + r0) * KTOT + kk;
  const short* gA1 = A + (size_t)(m0 + 64 + r0) * KTOT + kk;
  const short* gB0 = W + (size_t)(n0 + r0) * KTOT + kk;
  short* lA0 = As + wave * 512;  // wave-uniform base; HW scatters lane*16B
  short* lA1 = As + 2048 + wave * 512;
  short* lB0 = Bs + wave * 512;

  const int lr = lane & 15;
  const int qs = (lane >> 4) ^ ((lr >> 1) & 3);  // read-side swizzled chunk
  const int ko = qs * 8;

  for (int kt = 0; kt < KTOT; kt += 32) {
    __syncthreads();
    GLL(gA0 + kt, lA0);
    GLL(gA1 + kt, lA1);
    GLL(gB0 + kt, lB0);
    __syncthreads();
    short8 af[4], bfr[2];
#pragma unroll
    for (int mi = 0; mi < 4; mi++)
      af[mi] = *(const short8*)&As[(wm * 64 + mi * 16 + lr) * 32 + ko];
#pragma unroll
    for (int nj = 0; nj < 2; nj++)
      bfr[nj] = *(const short8*)&Bs[(wn * 32 + nj * 16 + lr) * 32 + ko];
#pragma unroll
    for (int mi = 0; mi < 4; mi++)
#pragma unroll
      for (int nj = 0; nj < 2; nj++)
        acc[mi][nj] = __builtin_amdgcn_mfma_f32_16x16x32_bf16(
            af[mi], bfr[nj], acc[mi][nj], 0, 0, 0);
  }

  // C/D layout (m89-verified): col = lane&15, row = (lane>>4)*4 + reg
  const int q = lane >> 4;
#pragma unroll
  for (int mi = 0; mi < 4; mi++) {
#pragma unroll
    for (int nj = 0; nj < 2; nj++) {
      const int gcol = n0 + wn * 32 + nj * 16 + lr;
#pragma unroll
      for (int r = 0; r < 4; r++) {
        const int grow = m0 + wm * 64 + mi * 16 + q * 4 + r;
        out[(size_t)grow * D_OUT + gcol] = acc[mi][nj][r];
      }
    }
  }
}

extern "C" void kernel_launch(void* const* d_in, const int* in_sizes, int n_in,
                              void* d_out, int out_size, void* d_ws, size_t ws_size,
                              hipStream_t stream) {
  const float* x     = (const float*)d_in[0];
  const float* gamma = (const float*)d_in[1];
  const float* beta  = (const float*)d_in[2];
  const float* bw    = (const float*)d_in[3];
  const float* sw    = (const float*)d_in[4];
  float* out = (float*)d_out;

  short* W = (short*)d_ws;                         // 512 * 4608 bf16
  short* A = (short*)d_ws + (size_t)D_OUT * KTOT;  // 16384 * 4608 bf16

  wprep_kernel<<<D_OUT, 256, 0, stream>>>(bw, sw, W);
  act_kernel<<<ROWS / 4, 256, 0, stream>>>(x, gamma, beta, A);
  gemm_kernel<<<dim3(ROWS / 128, D_OUT / 64), 256, 0, stream>>>(A, W, out);
}

// Round 3
// 220.125 us; speedup vs baseline: 1.0848x; 1.0608x over previous
//
#include <hip/hip_runtime.h>
#include <stdint.h>
#include <math.h>

// BSRBF-KAN layer: out = relu(LN(x)) @ base_W^T + (bspline(LN(x)) + rbf(LN(x))) @ spline_W^T
// One bf16 MFMA GEMM, K = 512 + 512*8 = 4608.
//   ws: [W: 512*4608 bf16][A: 16384*4608 bf16]
// GEMM: 128x128 tile, BK=64 (half the barriers of m97's BK=32), 4 waves,
// 16x16x32 bf16 MFMA, global_load_lds width=16, XOR bank swizzle (R2: 0 conflicts),
// XCD-aware block mapping.

#define D_IN  512
#define D_OUT 512
#define NB    8
#define KTOT  (D_IN + D_IN * NB)   // 4608
#define ROWS  16384                // B*S

typedef __attribute__((ext_vector_type(8))) short short8;
typedef __attribute__((ext_vector_type(4))) float f32x4;

__device__ __forceinline__ short f2bf(float f) {
  union { float f; unsigned u; } v; v.f = f;
  unsigned r = (v.u + 0x7fffu + ((v.u >> 16) & 1u)) >> 16;  // RNE, finite inputs
  return (short)r;
}

// ---------------- weight prep: interleave + fp32->bf16 -------------------
__global__ __launch_bounds__(256) void wprep_kernel(
    const float* __restrict__ bw, const float* __restrict__ sw,
    short* __restrict__ W) {
  const int o = blockIdx.x;
  for (int k = threadIdx.x; k < KTOT; k += 256) {
    const float v = (k < D_IN) ? bw[o * D_IN + k]
                               : sw[(size_t)o * (D_IN * NB) + (k - D_IN)];
    W[(size_t)o * KTOT + k] = f2bf(v);
  }
}

// ---------------- LN + relu + bspline + rbf -> bf16 A matrix -------------
// one wave per row; lane owns elements d = e*64 + lane
__global__ __launch_bounds__(256) void act_kernel(
    const float* __restrict__ x, const float* __restrict__ gamma,
    const float* __restrict__ beta, short* __restrict__ A) {
  const int tid = threadIdx.x;
  const int lane = tid & 63, wave = tid >> 6;
  const int row = blockIdx.x * 4 + wave;
  const float* xr = x + (size_t)row * D_IN;

  float xv[8];
  float s = 0.0f, ss = 0.0f;
#pragma unroll
  for (int e = 0; e < 8; e++) {
    xv[e] = xr[e * 64 + lane];
    s += xv[e];
    ss += xv[e] * xv[e];
  }
#pragma unroll
  for (int off = 32; off > 0; off >>= 1) {
    s += __shfl_xor(s, off);
    ss += __shfl_xor(ss, off);
  }
  const float mu = s * (1.0f / D_IN);
  const float var = ss * (1.0f / D_IN) - mu * mu;
  const float rstd = 1.0f / sqrtf(var + 1e-5f);

  short* Ar = A + (size_t)row * KTOT;
#pragma unroll
  for (int e = 0; e < 8; e++) {
    const int d = e * 64 + lane;
    const float xn = (xv[e] - mu) * rstd * gamma[d] + beta[d];
    Ar[d] = f2bf(fmaxf(xn, 0.0f));

    // closed-form uniform cubic B-spline, knots (i-3)*0.6 - 1.5
    const float u = (xn + 3.3f) * (1.0f / 0.6f);
    const float cf = floorf(u);
    const int c = (int)cf;
    const bool in = (c >= 0) && (c <= 10);
    const float t = u - cf;
    const float t2 = t * t, t3 = t2 * t;
    const float omt = 1.0f - t;
    float v0 = t3 * (1.0f / 6.0f);
    float v1 = (1.0f / 6.0f) * (1.0f + 3.0f * t + 3.0f * t2 - 3.0f * t3);
    float v2 = (1.0f / 6.0f) * (4.0f - 6.0f * t2 + 3.0f * t3);
    float v3 = (1.0f / 6.0f) * omt * omt * omt;
    if (!in) { v0 = 0.0f; v1 = 0.0f; v2 = 0.0f; v3 = 0.0f; }

    union { short sh[8]; int4 v; } o;
#pragma unroll
    for (int j = 0; j < 8; j++) {
      const int m = c - j;
      float sp = 0.0f;
      sp = (m == 0) ? v0 : sp;
      sp = (m == 1) ? v1 : sp;
      sp = (m == 2) ? v2 : sp;
      sp = (m == 3) ? v3 : sp;
      const float tt = (xn - (-1.5f + (float)j * (3.0f / 7.0f))) * (7.0f / 3.0f);
      const float rb = __builtin_amdgcn_exp2f(tt * tt * -1.442695040888963f);
      o.sh[j] = f2bf(sp + rb);
    }
    *(int4*)&Ar[D_IN + d * NB] = o.v;  // coalesced 1KB/wave
  }
}

// ---------------- bf16 MFMA GEMM: C[M,N] = A[M,K] * W[N,K]^T -------------
// LDS layout (per matrix): row r (0..127) x 64 k, as 8 chunks of 8 shorts.
// Slot (r, c) holds global chunk  c ^ (r & 7)  -> zero-ish bank conflicts:
// within a 16-lane read phase each bank-group is hit 2x (free, m136).
#define GLL(g, l)                                               \
  __builtin_amdgcn_global_load_lds(                             \
      (const __attribute__((address_space(1))) void*)(g),       \
      (__attribute__((address_space(3))) void*)(l), 16, 0, 0)

__global__ __launch_bounds__(256, 2) void gemm_kernel(
    const short* __restrict__ A, const short* __restrict__ W,
    float* __restrict__ out) {
  __shared__ short As[128 * 64];  // 16 KB
  __shared__ short Bs[128 * 64];  // 16 KB
  const int tid = threadIdx.x;
  const int lane = tid & 63, wave = tid >> 6;

  // XCD-aware mapping: blocks with same (f & 7) land on one XCD (round-robin
  // heuristic) and share one 128-col B panel.
  const int f = blockIdx.x;
  const int c8 = f & 7, g = f >> 3;                // g in 0..63
  const int m0 = (g + ((c8 >> 2) << 6)) * 128;     // 0..127 m-tiles
  const int n0 = (c8 & 3) * 128;                   // 0..3 n-tiles
  const int wm = wave & 1, wn = wave >> 1;

  const f32x4 zero = {0.0f, 0.0f, 0.0f, 0.0f};
  f32x4 acc[4][4];
#pragma unroll
  for (int i = 0; i < 4; i++)
#pragma unroll
    for (int j = 0; j < 4; j++) acc[i][j] = zero;

  // staging: thread -> (row r0 = tid>>3 in 0..31, chunk-slot c0 = tid&7);
  // 4 rounds add +32 rows. Source global chunk = c0 ^ (r0 & 7); (r0+32r)&7
  // is invariant, so one pointer per matrix + row-stride offsets.
  const int r0 = tid >> 3;
  const int c0 = tid & 7;
  const int qsrc = c0 ^ (r0 & 7);
  const short* gA = A + (size_t)(m0 + r0) * KTOT + qsrc * 8;
  const short* gB = W + (size_t)(n0 + r0) * KTOT + qsrc * 8;
  short* lA = As + wave * 512;  // wave-uniform base; HW scatters lane*16B
  short* lB = Bs + wave * 512;

  const int lr = lane & 15;
  const int q = lane >> 4;
  const int x7 = lr & 7;

  for (int kt = 0; kt < KTOT; kt += 64) {
    __syncthreads();
#pragma unroll
    for (int rd = 0; rd < 4; rd++) {
      GLL(gA + (size_t)(32 * rd) * KTOT + kt, lA + rd * 2048);
      GLL(gB + (size_t)(32 * rd) * KTOT + kt, lB + rd * 2048);
    }
    __syncthreads();
#pragma unroll
    for (int kk2 = 0; kk2 < 2; kk2++) {
      const int gq = kk2 * 4 + q;   // global chunk this lane consumes
      short8 af[4], bf[4];
#pragma unroll
      for (int mi = 0; mi < 4; mi++)
        af[mi] = *(const short8*)&As[(wm * 64 + mi * 16 + lr) * 64 + ((gq ^ x7) * 8)];
#pragma unroll
      for (int nj = 0; nj < 4; nj++)
        bf[nj] = *(const short8*)&Bs[(wn * 64 + nj * 16 + lr) * 64 + ((gq ^ x7) * 8)];
#pragma unroll
      for (int mi = 0; mi < 4; mi++)
#pragma unroll
        for (int nj = 0; nj < 4; nj++)
          acc[mi][nj] = __builtin_amdgcn_mfma_f32_16x16x32_bf16(
              af[mi], bf[nj], acc[mi][nj], 0, 0, 0);
    }
  }

  // C/D layout (m89-verified): col = lane&15, row = (lane>>4)*4 + reg
#pragma unroll
  for (int mi = 0; mi < 4; mi++) {
#pragma unroll
    for (int nj = 0; nj < 4; nj++) {
      const int gcol = n0 + wn * 64 + nj * 16 + lr;
#pragma unroll
      for (int r = 0; r < 4; r++) {
        const int grow = m0 + wm * 64 + mi * 16 + q * 4 + r;
        out[(size_t)grow * D_OUT + gcol] = acc[mi][nj][r];
      }
    }
  }
}

extern "C" void kernel_launch(void* const* d_in, const int* in_sizes, int n_in,
                              void* d_out, int out_size, void* d_ws, size_t ws_size,
                              hipStream_t stream) {
  const float* x     = (const float*)d_in[0];
  const float* gamma = (const float*)d_in[1];
  const float* beta  = (const float*)d_in[2];
  const float* bw    = (const float*)d_in[3];
  const float* sw    = (const float*)d_in[4];
  float* out = (float*)d_out;

  short* W = (short*)d_ws;                         // 512 * 4608 bf16
  short* A = (short*)d_ws + (size_t)D_OUT * KTOT;  // 16384 * 4608 bf16

  wprep_kernel<<<D_OUT, 256, 0, stream>>>(bw, sw, W);
  act_kernel<<<ROWS / 4, 256, 0, stream>>>(x, gamma, beta, A);
  gemm_kernel<<<512, 256, 0, stream>>>(A, W, out);
}

// Round 4
// 218.020 us; speedup vs baseline: 1.0953x; 1.0097x over previous
//
#include <hip/hip_runtime.h>
#include <stdint.h>
#include <math.h>

// BSRBF-KAN layer: out = relu(LN(x)) @ base_W^T + (bspline(LN(x)) + rbf(LN(x))) @ spline_W^T
// One bf16 MFMA GEMM, K = 512 + 512*8 = 4608.
//   ws: [W: 512*4608 bf16][A: 16384*4608 bf16]
// GEMM: 128x128 tile, BK=64, 4 waves, 16x16x32 bf16 MFMA, global_load_lds
// width=16, XOR bank swizzle (0 conflicts measured), n-minor block order so
// concurrent blocks share each A m-tile through L3.
// act: wave-per-row, closed-form cubic B-spline + RBF, register-only packing
// (no union punning -> no scratch).

#define D_IN  512
#define D_OUT 512
#define NB    8
#define KTOT  (D_IN + D_IN * NB)   // 4608
#define ROWS  16384                // B*S

typedef __attribute__((ext_vector_type(8))) short short8;
typedef __attribute__((ext_vector_type(4))) float f32x4;

__device__ __forceinline__ unsigned f2bfu(float f) {
  union { float f; unsigned u; } v; v.f = f;
  return (v.u + 0x7fffu + ((v.u >> 16) & 1u)) >> 16;  // RNE, finite inputs
}
__device__ __forceinline__ short f2bf(float f) { return (short)f2bfu(f); }

// ---------------- weight prep: interleave + fp32->bf16 -------------------
__global__ __launch_bounds__(256) void wprep_kernel(
    const float* __restrict__ bw, const float* __restrict__ sw,
    short* __restrict__ W) {
  const int o = blockIdx.x;
  for (int k = threadIdx.x; k < KTOT; k += 256) {
    const float v = (k < D_IN) ? bw[o * D_IN + k]
                               : sw[(size_t)o * (D_IN * NB) + (k - D_IN)];
    W[(size_t)o * KTOT + k] = f2bf(v);
  }
}

// ---------------- LN + relu + bspline + rbf -> bf16 A matrix -------------
// one wave per row; lane owns elements d = e*64 + lane
__global__ __launch_bounds__(256) void act_kernel(
    const float* __restrict__ x, const float* __restrict__ gamma,
    const float* __restrict__ beta, short* __restrict__ A) {
  const int tid = threadIdx.x;
  const int lane = tid & 63, wave = tid >> 6;
  const int row = blockIdx.x * 4 + wave;
  const float* xr = x + (size_t)row * D_IN;

  float xv[8];
  float s = 0.0f, ss = 0.0f;
#pragma unroll
  for (int e = 0; e < 8; e++) {
    xv[e] = xr[e * 64 + lane];
    s += xv[e];
    ss += xv[e] * xv[e];
  }
#pragma unroll
  for (int off = 32; off > 0; off >>= 1) {
    s += __shfl_xor(s, off);
    ss += __shfl_xor(ss, off);
  }
  const float mu = s * (1.0f / D_IN);
  const float var = ss * (1.0f / D_IN) - mu * mu;
  const float rstd = 1.0f / sqrtf(var + 1e-5f);

  short* Ar = A + (size_t)row * KTOT;
#pragma unroll
  for (int e = 0; e < 8; e++) {
    const int d = e * 64 + lane;
    const float xn = (xv[e] - mu) * rstd * gamma[d] + beta[d];
    Ar[d] = f2bf(fmaxf(xn, 0.0f));

    // closed-form uniform cubic B-spline, knots (i-3)*0.6 - 1.5
    const float u = (xn + 3.3f) * (1.0f / 0.6f);
    const float cf = floorf(u);
    const int c = (int)cf;
    const bool in = (c >= 0) && (c <= 10);
    const float t = u - cf;
    const float t2 = t * t, t3 = t2 * t;
    const float omt = 1.0f - t;
    float v0 = t3 * (1.0f / 6.0f);
    float v1 = (1.0f / 6.0f) * (1.0f + 3.0f * t + 3.0f * t2 - 3.0f * t3);
    float v2 = (1.0f / 6.0f) * (4.0f - 6.0f * t2 + 3.0f * t3);
    float v3 = (1.0f / 6.0f) * omt * omt * omt;
    if (!in) { v0 = 0.0f; v1 = 0.0f; v2 = 0.0f; v3 = 0.0f; }

    unsigned pk[4];
#pragma unroll
    for (int h = 0; h < 4; h++) {  // j = 2h, 2h+1
      unsigned lo, hi;
#pragma unroll
      for (int sub = 0; sub < 2; sub++) {
        const int j = 2 * h + sub;
        const int m = c - j;
        float sp = 0.0f;
        sp = (m == 0) ? v0 : sp;
        sp = (m == 1) ? v1 : sp;
        sp = (m == 2) ? v2 : sp;
        sp = (m == 3) ? v3 : sp;
        const float tt = (xn - (-1.5f + (float)j * (3.0f / 7.0f))) * (7.0f / 3.0f);
        const float rb = __builtin_amdgcn_exp2f(tt * tt * -1.442695040888963f);
        const unsigned b = f2bfu(sp + rb);
        if (sub == 0) lo = b; else hi = b;
      }
      pk[h] = lo | (hi << 16);
    }
    const uint4 v4 = {pk[0], pk[1], pk[2], pk[3]};
    *(uint4*)&Ar[D_IN + d * NB] = v4;  // coalesced 1KB/wave, registers only
  }
}

// ---------------- bf16 MFMA GEMM: C[M,N] = A[M,K] * W[N,K]^T -------------
// LDS layout (per matrix): row r (0..127) x 64 k, as 8 chunks of 8 shorts.
// Slot (r, c) holds global chunk  c ^ (r & 7)  -> zero bank conflicts (R2/R3).
#define GLL(g, l)                                               \
  __builtin_amdgcn_global_load_lds(                             \
      (const __attribute__((address_space(1))) void*)(g),       \
      (__attribute__((address_space(3))) void*)(l), 16, 0, 0)

__global__ __launch_bounds__(256, 2) void gemm_kernel(
    const short* __restrict__ A, const short* __restrict__ W,
    float* __restrict__ out) {
  __shared__ short As[128 * 64];  // 16 KB
  __shared__ short Bs[128 * 64];  // 16 KB
  const int tid = threadIdx.x;
  const int lane = tid & 63, wave = tid >> 6;

  // n-minor order: blocks {4g..4g+3} share one A m-tile and hit 4 different
  // XCDs concurrently -> L3 serves the cross-panel A re-reads.
  const int f = blockIdx.x;
  const int m0 = (f >> 2) * 128;
  const int n0 = (f & 3) * 128;
  const int wm = wave & 1, wn = wave >> 1;

  const f32x4 zero = {0.0f, 0.0f, 0.0f, 0.0f};
  f32x4 acc[4][4];
#pragma unroll
  for (int i = 0; i < 4; i++)
#pragma unroll
    for (int j = 0; j < 4; j++) acc[i][j] = zero;

  // staging: thread -> (row r0 = tid>>3 in 0..31, chunk-slot c0 = tid&7);
  // 4 rounds add +32 rows. Source global chunk = c0 ^ (r0 & 7).
  const int r0 = tid >> 3;
  const int c0 = tid & 7;
  const int qsrc = c0 ^ (r0 & 7);
  const short* gA = A + (size_t)(m0 + r0) * KTOT + qsrc * 8;
  const short* gB = W + (size_t)(n0 + r0) * KTOT + qsrc * 8;
  short* lA = As + wave * 512;  // wave-uniform base; HW scatters lane*16B
  short* lB = Bs + wave * 512;

  const int lr = lane & 15;
  const int q = lane >> 4;
  const int x7 = lr & 7;

  for (int kt = 0; kt < KTOT; kt += 64) {
    __syncthreads();
#pragma unroll
    for (int rd = 0; rd < 4; rd++) {
      GLL(gA + (size_t)(32 * rd) * KTOT + kt, lA + rd * 2048);
      GLL(gB + (size_t)(32 * rd) * KTOT + kt, lB + rd * 2048);
    }
    __syncthreads();
#pragma unroll
    for (int kk2 = 0; kk2 < 2; kk2++) {
      const int gq = kk2 * 4 + q;   // global chunk this lane consumes
      short8 af[4], bf[4];
#pragma unroll
      for (int mi = 0; mi < 4; mi++)
        af[mi] = *(const short8*)&As[(wm * 64 + mi * 16 + lr) * 64 + ((gq ^ x7) * 8)];
#pragma unroll
      for (int nj = 0; nj < 4; nj++)
        bf[nj] = *(const short8*)&Bs[(wn * 64 + nj * 16 + lr) * 64 + ((gq ^ x7) * 8)];
#pragma unroll
      for (int mi = 0; mi < 4; mi++)
#pragma unroll
        for (int nj = 0; nj < 4; nj++)
          acc[mi][nj] = __builtin_amdgcn_mfma_f32_16x16x32_bf16(
              af[mi], bf[nj], acc[mi][nj], 0, 0, 0);
    }
  }

  // C/D layout (m89-verified): col = lane&15, row = (lane>>4)*4 + reg
#pragma unroll
  for (int mi = 0; mi < 4; mi++) {
#pragma unroll
    for (int nj = 0; nj < 4; nj++) {
      const int gcol = n0 + wn * 64 + nj * 16 + lr;
#pragma unroll
      for (int r = 0; r < 4; r++) {
        const int grow = m0 + wm * 64 + mi * 16 + q * 4 + r;
        out[(size_t)grow * D_OUT + gcol] = acc[mi][nj][r];
      }
    }
  }
}

extern "C" void kernel_launch(void* const* d_in, const int* in_sizes, int n_in,
                              void* d_out, int out_size, void* d_ws, size_t ws_size,
                              hipStream_t stream) {
  const float* x     = (const float*)d_in[0];
  const float* gamma = (const float*)d_in[1];
  const float* beta  = (const float*)d_in[2];
  const float* bw    = (const float*)d_in[3];
  const float* sw    = (const float*)d_in[4];
  float* out = (float*)d_out;

  short* W = (short*)d_ws;                         // 512 * 4608 bf16
  short* A = (short*)d_ws + (size_t)D_OUT * KTOT;  // 16384 * 4608 bf16

  wprep_kernel<<<D_OUT, 256, 0, stream>>>(bw, sw, W);
  act_kernel<<<ROWS / 4, 256, 0, stream>>>(x, gamma, beta, A);
  gemm_kernel<<<512, 256, 0, stream>>>(A, W, out);
}